// Round 5
// baseline (284.060 us; speedup 1.0000x reference)
//
#include <hip/hip_runtime.h>
#include <hip/hip_bf16.h>

typedef __attribute__((ext_vector_type(4))) float  f32x4;
typedef __attribute__((ext_vector_type(8))) short  bf16x8;
typedef __attribute__((ext_vector_type(4))) short  bf16x4v;

#define BM 64
#define BN 128
#define BK 32
#define PADK 36   // bf16 elems per LDS row (72 B; rows start on distinct banks)
#define EPAD 68   // f32 elems per epilogue LDS row (64 + 4 pad)

// LDS budget: dbuf = 2*(64*36*2 + 128*36*2) = 27648 B ; Es = 4*16*68*4 = 17408 B
#define SMEM_BYTES 27648

__device__ __forceinline__ unsigned short f2bf(float f) {
  __hip_bfloat16 h = __float2bfloat16(f);
  unsigned short u; __builtin_memcpy(&u, &h, 2); return u;
}

// Fully-inline sincos: f64 Cody-Waite reduction (x ~ N(0,1), small |k|),
// musl-style f32 kernels. No libcall -> no ABI spill traffic (round-3 lesson).
__device__ __forceinline__ void my_sincos(float xf, float& s_out, float& c_out) {
  const double xd = (double)xf;
  const double kd = __builtin_rint(xd * 0.636619772367581343076);   // x * 2/pi
  const int    q  = (int)kd;
  double rd = __builtin_fma(-kd, 1.5707963267948966,    xd);        // pio2_hi (f64)
  rd        = __builtin_fma(-kd, 6.123233995736766e-17, rd);        // pio2_lo
  const float r = (float)rd;
  const float z = r * r;
  const float ps = fmaf(z, fmaf(z, fmaf(z, 2.7183114939898219e-06f,
                                           -1.9839334836096632e-04f),
                                   8.3333293858894632e-03f),
                        -1.6666666641626524e-01f);
  const float sr = fmaf(r * z, ps, r);                              // sin(r)
  const float pc = fmaf(z, fmaf(z, fmaf(z, 2.4390448796277409e-05f,
                                           -1.3886763774609929e-03f),
                                   4.1666623323739063e-02f),
                        -4.9999999725103100e-01f);
  const float cr = fmaf(z, pc, 1.0f);                               // cos(r)
  const bool swap = (q & 1) != 0;
  float s1 = swap ? cr : sr;
  float c1 = swap ? sr : cr;
  if (q & 2)       s1 = -s1;
  if ((q + 1) & 2) c1 = -c1;
  s_out = s1; c_out = c1;
}

// ---- kernel 1: W (H,H) f32 row-major -> Wt (H,H) bf16, transposed ----
__global__ __launch_bounds__(256)
void transpose_W(const float* __restrict__ W, unsigned short* __restrict__ Wt, int H) {
  __shared__ float tile[64][65];
  const int k0 = blockIdx.y * 64;
  const int n0 = blockIdx.x * 64;
  const int t = threadIdx.x;
  #pragma unroll
  for (int it = 0; it < 4; ++it) {
    int q = it * 256 + t;
    int r = q >> 4, c4 = (q & 15) << 2;
    f32x4 v = *(const f32x4*)&W[(size_t)(k0 + r) * H + n0 + c4];
    tile[r][c4 + 0] = v[0]; tile[r][c4 + 1] = v[1];
    tile[r][c4 + 2] = v[2]; tile[r][c4 + 3] = v[3];
  }
  __syncthreads();
  #pragma unroll
  for (int it = 0; it < 4; ++it) {
    int q = it * 256 + t;
    int r = q >> 4, c4 = (q & 15) << 2;
    bf16x4v o;
    #pragma unroll
    for (int j = 0; j < 4; ++j) o[j] = (short)f2bf(tile[c4 + j][r]);
    *(bf16x4v*)&Wt[(size_t)(n0 + r) * H + k0 + c4] = o;
  }
}

// ---- kernel 1b: x f32 -> bf16 ----
__global__ __launch_bounds__(256)
void cvt_x(const float* __restrict__ x, unsigned short* __restrict__ xb, int n4) {
  int i = blockIdx.x * 256 + threadIdx.x;
  const int stride = gridDim.x * 256;
  for (; i < n4; i += stride) {
    f32x4 v = ((const f32x4*)x)[i];
    bf16x4v o;
    #pragma unroll
    for (int j = 0; j < 4; ++j) o[j] = (short)f2bf(v[j]);
    ((bf16x4v*)xb)[i] = o;
  }
}

// ---- kernel 2: fused bf16-MFMA GEMM + inline trig epilogue + ODE scale ----
// Structure: reg-staged (compiler-hoistable loads) + explicit 1-deep prefetch
// + double-buffered LDS + ONE barrier per K-step (round-4 lesson: LDS-dest
// loads serialize on the WAR barrier; VGPR-dest loads don't).
template <bool XB>
__global__ __launch_bounds__(256, 4)
void gemm_fused(const float* __restrict__ x, const unsigned short* __restrict__ xb,
                const unsigned short* __restrict__ Wt,
                const float* __restrict__ bv, const float* __restrict__ cv,
                const float* __restrict__ dv, float* __restrict__ out,
                float S, int H) {
  __shared__ unsigned char smem[SMEM_BYTES];
  float* Es = (float*)smem;                      // epilogue-lifetime overlay

  const int tid  = threadIdx.x;
  const int bj   = blockIdx.x;       // N tile (8) -- fast dim: A-panel concurrency
  const int bi   = blockIdx.y;       // M tile (256)
  const int i0   = bi * BM, j0 = bj * BN;
  const int wave = tid >> 6, lane = tid & 63;
  const int wr = wave >> 1, wc = wave & 1;       // wave owns 32x64 of C
  const int l16 = lane & 15, lq = lane >> 4;

  f32x4 acc[2][4] = {};

  if constexpr (XB) {
    unsigned short* A0 = (unsigned short*)smem;                  // [64][36]
    unsigned short* B0 = A0 + BM * PADK;                         // [128][36]
    unsigned short* A1 = B0 + BN * PADK;
    unsigned short* B1 = A1 + BM * PADK;

    // per-thread staging coords (16 B each)
    const int ar  = tid >> 2,            ak  = (tid & 3) << 3;   // A: 1 load
    const int br0 = tid >> 2,            bk0 = (tid & 3) << 3;   // B: 2 loads
    const int br1 = (256 + tid) >> 2,    bk1 = (tid & 3) << 3;
    const unsigned short* aP = &xb[(size_t)(i0 + ar ) * H + ak ];
    const unsigned short* bP0 = &Wt[(size_t)(j0 + br0) * H + bk0];
    const unsigned short* bP1 = &Wt[(size_t)(j0 + br1) * H + bk1];

    // prologue: stage tile 0 into buf0
    {
      bf16x8 pa  = *(const bf16x8*)(aP);
      bf16x8 pb0 = *(const bf16x8*)(bP0);
      bf16x8 pb1 = *(const bf16x8*)(bP1);
      *(bf16x8*)&A0[ar * PADK + ak ] = pa;
      *(bf16x8*)&B0[br0 * PADK + bk0] = pb0;
      *(bf16x8*)&B0[br1 * PADK + bk1] = pb1;
    }
    __syncthreads();

    for (int kk = 0; kk < H; kk += 2 * BK) {
      // ---- sub-step A: prefetch tile(kk+BK), compute buf0, write buf1 ----
      {
        bf16x8 pa  = *(const bf16x8*)(aP  + kk + BK);
        bf16x8 pb0 = *(const bf16x8*)(bP0 + kk + BK);
        bf16x8 pb1 = *(const bf16x8*)(bP1 + kk + BK);
        bf16x8 af[2], bfr[4];
        #pragma unroll
        for (int mi = 0; mi < 2; ++mi)
          af[mi] = *(const bf16x8*)&A0[(wr * 32 + mi * 16 + l16) * PADK + lq * 8];
        #pragma unroll
        for (int ni = 0; ni < 4; ++ni)
          bfr[ni] = *(const bf16x8*)&B0[(wc * 64 + ni * 16 + l16) * PADK + lq * 8];
        #pragma unroll
        for (int mi = 0; mi < 2; ++mi)
          #pragma unroll
          for (int ni = 0; ni < 4; ++ni)
            acc[mi][ni] = __builtin_amdgcn_mfma_f32_16x16x32_bf16(af[mi], bfr[ni], acc[mi][ni], 0, 0, 0);
        *(bf16x8*)&A1[ar * PADK + ak ] = pa;
        *(bf16x8*)&B1[br0 * PADK + bk0] = pb0;
        *(bf16x8*)&B1[br1 * PADK + bk1] = pb1;
      }
      __syncthreads();
      // ---- sub-step B: prefetch tile(kk+2BK), compute buf1, write buf0 ----
      {
        const bool more = (kk + 2 * BK) < H;
        bf16x8 pa, pb0, pb1;
        if (more) {
          pa  = *(const bf16x8*)(aP  + kk + 2 * BK);
          pb0 = *(const bf16x8*)(bP0 + kk + 2 * BK);
          pb1 = *(const bf16x8*)(bP1 + kk + 2 * BK);
        }
        bf16x8 af[2], bfr[4];
        #pragma unroll
        for (int mi = 0; mi < 2; ++mi)
          af[mi] = *(const bf16x8*)&A1[(wr * 32 + mi * 16 + l16) * PADK + lq * 8];
        #pragma unroll
        for (int ni = 0; ni < 4; ++ni)
          bfr[ni] = *(const bf16x8*)&B1[(wc * 64 + ni * 16 + l16) * PADK + lq * 8];
        #pragma unroll
        for (int mi = 0; mi < 2; ++mi)
          #pragma unroll
          for (int ni = 0; ni < 4; ++ni)
            acc[mi][ni] = __builtin_amdgcn_mfma_f32_16x16x32_bf16(af[mi], bfr[ni], acc[mi][ni], 0, 0, 0);
        if (more) {
          *(bf16x8*)&A0[ar * PADK + ak ] = pa;
          *(bf16x8*)&B0[br0 * PADK + bk0] = pb0;
          *(bf16x8*)&B0[br1 * PADK + bk1] = pb1;
        }
      }
      __syncthreads();
    }
  } else {
    // fallback: single-buffer, f32->bf16 convert staging
    unsigned short* As = (unsigned short*)smem;
    unsigned short* Bs = As + BM * PADK;
    for (int kk = 0; kk < H; kk += BK) {
      #pragma unroll
      for (int it = 0; it < 2; ++it) {
        int q = it * 256 + tid;
        int r = q >> 3, k4 = (q & 7) << 2;
        f32x4 v = *(const f32x4*)&x[(size_t)(i0 + r) * H + kk + k4];
        bf16x4v o;
        #pragma unroll
        for (int j = 0; j < 4; ++j) o[j] = (short)f2bf(v[j]);
        *(bf16x4v*)&As[r * PADK + k4] = o;
      }
      #pragma unroll
      for (int it = 0; it < 2; ++it) {
        int q = it * 256 + tid;
        int r = q >> 2, k8 = (q & 3) << 3;
        bf16x8 v = *(const bf16x8*)&Wt[(size_t)(j0 + r) * H + kk + k8];
        *(bf16x8*)&Bs[r * PADK + k8] = v;
      }
      __syncthreads();
      bf16x8 af[2], bfr[4];
      #pragma unroll
      for (int mi = 0; mi < 2; ++mi)
        af[mi] = *(const bf16x8*)&As[(wr * 32 + mi * 16 + l16) * PADK + lq * 8];
      #pragma unroll
      for (int ni = 0; ni < 4; ++ni)
        bfr[ni] = *(const bf16x8*)&Bs[(wc * 64 + ni * 16 + l16) * PADK + lq * 8];
      #pragma unroll
      for (int mi = 0; mi < 2; ++mi)
        #pragma unroll
        for (int ni = 0; ni < 4; ++ni)
          acc[mi][ni] = __builtin_amdgcn_mfma_f32_16x16x32_bf16(af[mi], bfr[ni], acc[mi][ni], 0, 0, 0);
      __syncthreads();
    }
  }

  // ---- epilogue: per-wave LDS transpose, coalesced f32x4 IO, inline trig ----
  // C/D fragment layout: col = l16, row = lq*4 + r  [m89-verified]
  float* ep = Es + wave * (16 * EPAD);
  const int rr = lane >> 2;           // 0..15
  const int cq = (lane & 3) * 16;     // 0,16,32,48
  #pragma unroll
  for (int mi = 0; mi < 2; ++mi) {
    #pragma unroll
    for (int ni = 0; ni < 4; ++ni)
      #pragma unroll
      for (int r = 0; r < 4; ++r)
        ep[(lq * 4 + r) * EPAD + ni * 16 + l16] = acc[mi][ni][r];
    // same-wave ds_write -> ds_read: in-order LDS pipe, compiler waits lgkmcnt.
    const int i  = i0 + wr * 32 + mi * 16 + rr;
    const int jb = j0 + wc * 64 + cq;
    const float* xrow = &x[(size_t)i * H + jb];
    float*       orow = &out[(size_t)i * H + jb];
    #pragma unroll
    for (int t = 0; t < 4; ++t) {
      f32x4 a  = *(const f32x4*)&ep[rr * EPAD + cq + 4 * t];
      f32x4 xv = *(const f32x4*)&xrow[4 * t];
      f32x4 b4 = *(const f32x4*)&bv[jb + 4 * t];
      f32x4 c4 = *(const f32x4*)&cv[jb + 4 * t];
      f32x4 d4 = *(const f32x4*)&dv[jb + 4 * t];
      f32x4 o;
      #pragma unroll
      for (int e = 0; e < 4; ++e) {
        float s, co;
        my_sincos(xv[e], s, co);
        o[e] = S * (a[e] + b4[e] * s + c4[e] * co + d4[e] * (s / co));
      }
      *(f32x4*)&orow[4 * t] = o;
    }
  }
}

extern "C" void kernel_launch(void* const* d_in, const int* in_sizes, int n_in,
                              void* d_out, int out_size, void* d_ws, size_t ws_size,
                              hipStream_t stream) {
  const float* x = (const float*)d_in[0];
  const float* W = (const float*)d_in[1];
  const float* b = (const float*)d_in[2];
  const float* c = (const float*)d_in[3];
  const float* d = (const float*)d_in[4];
  float* out = (float*)d_out;
  const int H = in_sizes[2];          // 1024
  const int M = in_sizes[0] / H;      // 16384

  // Scalar RK4 factor: y_final = S * z (ODE linear in y, y0 = 0).
  const int NT = 100;
  float ts[NT];
  const float step = (float)(1.0 / 99.0);
  for (int i = 0; i < NT; ++i) ts[i] = (float)i * step;
  ts[NT - 1] = 1.0f;
  double yy = 0.0;
  for (int i = 0; i < NT - 1; ++i) {
    const double t = (double)ts[i], dt = (double)(ts[i + 1] - ts[i]);
    const double k1 = t - yy;
    const double k2 = (t + 0.5 * dt) - (yy + 0.5 * dt * k1);
    const double k3 = (t + 0.5 * dt) - (yy + 0.5 * dt * k2);
    const double k4 = (t + dt) - (yy + dt * k3);
    yy += dt / 6.0 * (k1 + 2.0 * k2 + 2.0 * k3 + k4);
  }
  const float S = (float)yy;

  unsigned short* Wt = (unsigned short*)d_ws;                 // 2 MB bf16 W^T
  dim3 tgrid(H / 64, H / 64);
  transpose_W<<<tgrid, 256, 0, stream>>>(W, Wt, H);

  const size_t need = (size_t)H * H * 2 + (size_t)M * H * 2;  // Wt + x_bf16
  dim3 ggrid(H / BN, M / BM);                                 // (8, 256), bj fast

  if (ws_size >= need) {
    unsigned short* xb = Wt + (size_t)H * H;                  // 32 MB bf16 x
    cvt_x<<<2048, 256, 0, stream>>>(x, xb, M * H / 4);
    gemm_fused<true><<<ggrid, 256, 0, stream>>>(x, xb, Wt, b, c, d, out, S, H);
  } else {
    gemm_fused<false><<<ggrid, 256, 0, stream>>>(x, nullptr, Wt, b, c, d, out, S, H);
  }
}

// Round 6
// 83.914 us; speedup vs baseline: 3.3852x; 3.3852x over previous
//
#include <hip/hip_runtime.h>
#include <hip/hip_bf16.h>

typedef __attribute__((ext_vector_type(4))) float  f32x4;
typedef __attribute__((ext_vector_type(8))) short  bf16x8;
typedef __attribute__((ext_vector_type(4))) short  bf16x4v;

#define BM 128
#define BN 128
#define BK 64
#define PADK 72   // bf16/row: 144 B stride (16B-aligned), breaks pow2 bank stride
#define EPAD 68   // f32 elems per epilogue LDS row (64 + 4 pad)
#define SMEM_BYTES 36864   // As[128][72] + Bs[128][72] bf16; Es (17408 B) overlays

__device__ __forceinline__ unsigned short f2bf(float f) {
  __hip_bfloat16 h = __float2bfloat16(f);
  unsigned short u; __builtin_memcpy(&u, &h, 2); return u;
}

// Fully-inline sincos: f64 Cody-Waite reduction (x ~ N(0,1), tiny |k|),
// musl-style f32 kernels. No libcall -> no ABI spill traffic (round-3 lesson).
__device__ __forceinline__ void my_sincos(float xf, float& s_out, float& c_out) {
  const double xd = (double)xf;
  const double kd = __builtin_rint(xd * 0.636619772367581343076);   // x * 2/pi
  const int    q  = (int)kd;
  double rd = __builtin_fma(-kd, 1.5707963267948966,    xd);        // pio2_hi (f64)
  rd        = __builtin_fma(-kd, 6.123233995736766e-17, rd);        // pio2_lo
  const float r = (float)rd;
  const float z = r * r;
  const float ps = fmaf(z, fmaf(z, fmaf(z, 2.7183114939898219e-06f,
                                           -1.9839334836096632e-04f),
                                   8.3333293858894632e-03f),
                        -1.6666666641626524e-01f);
  const float sr = fmaf(r * z, ps, r);                              // sin(r)
  const float pc = fmaf(z, fmaf(z, fmaf(z, 2.4390448796277409e-05f,
                                           -1.3886763774609929e-03f),
                                   4.1666623323739063e-02f),
                        -4.9999999725103100e-01f);
  const float cr = fmaf(z, pc, 1.0f);                               // cos(r)
  const bool swap = (q & 1) != 0;
  float s1 = swap ? cr : sr;
  float c1 = swap ? sr : cr;
  if (q & 2)       s1 = -s1;
  if ((q + 1) & 2) c1 = -c1;
  s_out = s1; c_out = c1;
}

// ---- kernel 1: W (H,H) f32 row-major -> Wt (H,H) bf16, transposed ----
__global__ __launch_bounds__(256)
void transpose_W(const float* __restrict__ W, unsigned short* __restrict__ Wt, int H) {
  __shared__ float tile[64][65];
  const int k0 = blockIdx.y * 64;
  const int n0 = blockIdx.x * 64;
  const int t = threadIdx.x;
  #pragma unroll
  for (int it = 0; it < 4; ++it) {
    int q = it * 256 + t;
    int r = q >> 4, c4 = (q & 15) << 2;
    f32x4 v = *(const f32x4*)&W[(size_t)(k0 + r) * H + n0 + c4];
    tile[r][c4 + 0] = v[0]; tile[r][c4 + 1] = v[1];
    tile[r][c4 + 2] = v[2]; tile[r][c4 + 3] = v[3];
  }
  __syncthreads();
  #pragma unroll
  for (int it = 0; it < 4; ++it) {
    int q = it * 256 + t;
    int r = q >> 4, c4 = (q & 15) << 2;
    bf16x4v o;
    #pragma unroll
    for (int j = 0; j < 4; ++j) o[j] = (short)f2bf(tile[c4 + j][r]);
    *(bf16x4v*)&Wt[(size_t)(n0 + r) * H + k0 + c4] = o;
  }
}

// ---- kernel 1b: x f32 -> bf16 ----
__global__ __launch_bounds__(256)
void cvt_x(const float* __restrict__ x, unsigned short* __restrict__ xb, int n4) {
  int i = blockIdx.x * 256 + threadIdx.x;
  const int stride = gridDim.x * 256;
  for (; i < n4; i += stride) {
    f32x4 v = ((const f32x4*)x)[i];
    bf16x4v o;
    #pragma unroll
    for (int j = 0; j < 4; ++j) o[j] = (short)f2bf(v[j]);
    ((bf16x4v*)xb)[i] = o;
  }
}

// ---- kernel 2: fused bf16-MFMA GEMM + inline trig epilogue + ODE scale ----
// Round-3 structure (compiler-scheduled single-buffer, 2 barriers/K-step) --
// the compiler hoists next-tile global loads into the current MFMA phase,
// which IS the software pipeline (round-4/5 lesson: explicit structures
// that pin loads near their ds_write serialize on load latency).
// BK=64 halves barrier periods and doubles MFMA + loads-in-flight per period.
template <bool XB>
__global__ __launch_bounds__(256, 2)
void gemm_fused(const float* __restrict__ x, const unsigned short* __restrict__ xb,
                const unsigned short* __restrict__ Wt,
                const float* __restrict__ bv, const float* __restrict__ cv,
                const float* __restrict__ dv, float* __restrict__ out,
                float S, int H) {
  __shared__ unsigned char smem[SMEM_BYTES];
  unsigned short* As = (unsigned short*)smem;            // [128][72] bf16
  unsigned short* Bs = As + BM * PADK;                   // [128][72] bf16
  float*          Es = (float*)smem;                     // epilogue overlay

  const int tid  = threadIdx.x;
  // XCD-aware swizzle (bijective: gridDim.x = 1024, 1024 % 8 == 0).
  // Consecutive work-ids land on the SAME XCD -> each XCD sees all 8 bj
  // (full Wt, 2 MB, L2-resident) x 16 consecutive bi panels.
  const int nwg  = gridDim.x;
  const int work = (blockIdx.x & 7) * (nwg >> 3) + (blockIdx.x >> 3);
  const int bj   = work & 7;         // N tile (8), fast
  const int bi   = work >> 3;        // M tile (128)
  const int i0   = bi * BM, j0 = bj * BN;
  const int wave = tid >> 6, lane = tid & 63;
  const int wr = wave >> 1, wc = wave & 1;               // wave owns 64x64 of C
  const int l16 = lane & 15, lq = lane >> 4;

  f32x4 acc[4][4] = {};

  for (int kk = 0; kk < H; kk += BK) {
    if constexpr (XB) {
      // stage A tile: xb[128][kk..kk+64] bf16, 8 chunks/row, 4 per thread
      #pragma unroll
      for (int it = 0; it < 4; ++it) {
        int q = it * 256 + tid;            // 0..1023
        int r = q >> 3, c8 = (q & 7) << 3;
        bf16x8 v = *(const bf16x8*)&xb[(size_t)(i0 + r) * H + kk + c8];
        *(bf16x8*)&As[r * PADK + c8] = v;
      }
    } else {
      // stage A from f32 x with convert
      #pragma unroll
      for (int it = 0; it < 8; ++it) {
        int q = it * 256 + tid;            // 0..2047, 4 floats each
        int r = q >> 4, c4 = (q & 15) << 2;
        f32x4 v = *(const f32x4*)&x[(size_t)(i0 + r) * H + kk + c4];
        bf16x4v o;
        #pragma unroll
        for (int j = 0; j < 4; ++j) o[j] = (short)f2bf(v[j]);
        *(bf16x4v*)&As[r * PADK + c4] = o;
      }
    }
    // stage B tile: Wt[128][kk..kk+64] bf16
    #pragma unroll
    for (int it = 0; it < 4; ++it) {
      int q = it * 256 + tid;
      int r = q >> 3, c8 = (q & 7) << 3;
      bf16x8 v = *(const bf16x8*)&Wt[(size_t)(j0 + r) * H + kk + c8];
      *(bf16x8*)&Bs[r * PADK + c8] = v;
    }
    __syncthreads();

    #pragma unroll
    for (int s = 0; s < 2; ++s) {        // two K=32 subtiles
      bf16x8 af[4], bfr[4];
      #pragma unroll
      for (int mi = 0; mi < 4; ++mi)
        af[mi] = *(const bf16x8*)&As[(wr * 64 + mi * 16 + l16) * PADK + s * 32 + lq * 8];
      #pragma unroll
      for (int ni = 0; ni < 4; ++ni)
        bfr[ni] = *(const bf16x8*)&Bs[(wc * 64 + ni * 16 + l16) * PADK + s * 32 + lq * 8];
      #pragma unroll
      for (int mi = 0; mi < 4; ++mi)
        #pragma unroll
        for (int ni = 0; ni < 4; ++ni)
          acc[mi][ni] = __builtin_amdgcn_mfma_f32_16x16x32_bf16(af[mi], bfr[ni], acc[mi][ni], 0, 0, 0);
    }
    __syncthreads();
  }

  // ---- epilogue: per-wave LDS transpose, coalesced f32x4 IO, inline trig ----
  // C/D fragment layout: col = l16, row = lq*4 + r  [m89-verified]
  float* ep = Es + wave * (16 * EPAD);
  const int rr = lane >> 2;           // 0..15
  const int cq = (lane & 3) * 16;     // 0,16,32,48
  #pragma unroll
  for (int mi = 0; mi < 4; ++mi) {
    #pragma unroll
    for (int ni = 0; ni < 4; ++ni)
      #pragma unroll
      for (int r = 0; r < 4; ++r)
        ep[(lq * 4 + r) * EPAD + ni * 16 + l16] = acc[mi][ni][r];
    // same-wave ds_write -> ds_read: in-order LDS pipe, compiler waits lgkmcnt.
    const int i  = i0 + wr * 64 + mi * 16 + rr;
    const int jb = j0 + wc * 64 + cq;
    const float* xrow = &x[(size_t)i * H + jb];
    float*       orow = &out[(size_t)i * H + jb];
    #pragma unroll
    for (int t = 0; t < 4; ++t) {
      f32x4 a  = *(const f32x4*)&ep[rr * EPAD + cq + 4 * t];
      f32x4 xv = *(const f32x4*)&xrow[4 * t];
      f32x4 b4 = *(const f32x4*)&bv[jb + 4 * t];
      f32x4 c4 = *(const f32x4*)&cv[jb + 4 * t];
      f32x4 d4 = *(const f32x4*)&dv[jb + 4 * t];
      f32x4 o;
      #pragma unroll
      for (int e = 0; e < 4; ++e) {
        float s, co;
        my_sincos(xv[e], s, co);
        o[e] = S * (a[e] + b4[e] * s + c4[e] * co + d4[e] * (s / co));
      }
      *(f32x4*)&orow[4 * t] = o;
    }
  }
}

extern "C" void kernel_launch(void* const* d_in, const int* in_sizes, int n_in,
                              void* d_out, int out_size, void* d_ws, size_t ws_size,
                              hipStream_t stream) {
  const float* x = (const float*)d_in[0];
  const float* W = (const float*)d_in[1];
  const float* b = (const float*)d_in[2];
  const float* c = (const float*)d_in[3];
  const float* d = (const float*)d_in[4];
  float* out = (float*)d_out;
  const int H = in_sizes[2];          // 1024
  const int M = in_sizes[0] / H;      // 16384

  // Scalar RK4 factor: y_final = S * z (ODE linear in y, y0 = 0).
  const int NT = 100;
  float ts[NT];
  const float step = (float)(1.0 / 99.0);
  for (int i = 0; i < NT; ++i) ts[i] = (float)i * step;
  ts[NT - 1] = 1.0f;
  double yy = 0.0;
  for (int i = 0; i < NT - 1; ++i) {
    const double t = (double)ts[i], dt = (double)(ts[i + 1] - ts[i]);
    const double k1 = t - yy;
    const double k2 = (t + 0.5 * dt) - (yy + 0.5 * dt * k1);
    const double k3 = (t + 0.5 * dt) - (yy + 0.5 * dt * k2);
    const double k4 = (t + dt) - (yy + dt * k3);
    yy += dt / 6.0 * (k1 + 2.0 * k2 + 2.0 * k3 + k4);
  }
  const float S = (float)yy;

  unsigned short* Wt = (unsigned short*)d_ws;                 // 2 MB bf16 W^T
  dim3 tgrid(H / 64, H / 64);
  transpose_W<<<tgrid, 256, 0, stream>>>(W, Wt, H);

  const size_t need = (size_t)H * H * 2 + (size_t)M * H * 2;  // Wt + x_bf16
  const int nblk = (H / BN) * (M / BM);                       // 1024, %8 == 0

  if (ws_size >= need) {
    unsigned short* xb = Wt + (size_t)H * H;                  // 32 MB bf16 x
    cvt_x<<<2048, 256, 0, stream>>>(x, xb, M * H / 4);
    gemm_fused<true><<<nblk, 256, 0, stream>>>(x, xb, Wt, b, c, d, out, S, H);
  } else {
    gemm_fused<false><<<nblk, 256, 0, stream>>>(x, nullptr, Wt, b, c, d, out, S, H);
  }
}